// Round 6
// baseline (261.785 us; speedup 1.0000x reference)
//
#include <hip/hip_runtime.h>
#include <hip/hip_bf16.h>
#include <math.h>

#define B_   2
#define H_   16
#define NSEQ 1024
#define DM   1024
#define DKV  64
#define NSPLIT 4
#define KPB  (NSEQ / NSPLIT)   // 256 keys per block
#define WMCH 16                // 64-key chunks per row
#define LNEPS 1e-5f

typedef __attribute__((ext_vector_type(8))) short s16x8;
typedef __attribute__((ext_vector_type(4))) short s16x4;
typedef __attribute__((ext_vector_type(4))) float f32x4;
typedef __attribute__((ext_vector_type(4))) unsigned u32x4;

__device__ inline short f2bf(float f) {
    __hip_bfloat16 h = __float2bfloat16(f);
    return *reinterpret_cast<short*>(&h);
}
__device__ inline float bf2f(short s) {
    unsigned u = ((unsigned)(unsigned short)s) << 16;
    return __uint_as_float(u);
}

// ---------------- mask dtype detection ----------------
__global__ void detect_mask(const unsigned* __restrict__ mask_words, int* __restrict__ flag) {
    unsigned f = 0;
    for (int i = 0; i < 256; ++i) f |= (mask_words[i] > 1u) ? 1u : 0u;
    *flag = (int)f;   // 1 => packed uint8 bools, 0 => int32 0/1
}

// ---------------- wgt+mask fused streamer ----------------
// wm[((bh*16 + ck)*NSEQ + q)*64 + kk] = mask ? -1.0 : 0.125*wgt   (bf16)
// Reads contiguous (1KB/instr wgt, 256B/instr mask), writes 128B segments.
// Converts the scattered in-attn pattern into an L3-resident tiled layout.
__global__ __launch_bounds__(256) void wm_stream(
    const void* __restrict__ mask, const float* __restrict__ wgt,
    const int* __restrict__ flagp, short* __restrict__ wm)
{
    const int t = threadIdx.x, wv = t >> 6, l = t & 63;
    const int qt = blockIdx.x, h = blockIdx.y, b = blockIdx.z;
    const size_t bh = (size_t)b * H_ + h;
    const int mmode = *flagp;
    const unsigned char* Mb = (const unsigned char*)mask;
    const unsigned* Mi = (const unsigned*)mask;

    for (int rr = 0; rr < 16; ++rr) {
        const int q = qt * 64 + wv * 16 + rr;
        const size_t roff = (bh * NSEQ + q) * NSEQ;
        #pragma unroll
        for (int it = 0; it < 4; ++it) {
            const int k = it * 256 + l * 4;
            f32x4 w4 = *(const f32x4*)(wgt + roff + k);
            unsigned m4[4];
            if (mmode) {
                uchar4 mb = *(const uchar4*)(Mb + roff + k);
                m4[0] = mb.x; m4[1] = mb.y; m4[2] = mb.z; m4[3] = mb.w;
            } else {
                u32x4 mi = *(const u32x4*)(Mi + roff + k);
                m4[0] = mi[0]; m4[1] = mi[1]; m4[2] = mi[2]; m4[3] = mi[3];
            }
            s16x4 o;
            #pragma unroll
            for (int r = 0; r < 4; ++r) {
                float v = m4[r] ? -1.0f : w4[r] * 0.125f;
                o[r] = f2bf(v);
            }
            const int ck = k >> 6, kk = k & 63;
            *(s16x4*)(wm + (((size_t)bh * WMCH + ck) * NSEQ + q) * 64 + kk) = o;
        }
    }
}

// ---------------- W[K][N] f32 -> Wt[N][K] bf16 (4 weights in one launch) ----------------
__global__ __launch_bounds__(256) void castT4_bf16(
    const float* __restrict__ w0, const float* __restrict__ w1,
    const float* __restrict__ w2, const float* __restrict__ w3,
    short* __restrict__ t0, short* __restrict__ t1,
    short* __restrict__ t2, short* __restrict__ t3) {
    const float* W = blockIdx.z == 0 ? w0 : (blockIdx.z == 1 ? w1 : (blockIdx.z == 2 ? w2 : w3));
    short* Wt      = blockIdx.z == 0 ? t0 : (blockIdx.z == 1 ? t1 : (blockIdx.z == 2 ? t2 : t3));
    __shared__ float tl[32][33];
    const int k0 = blockIdx.y * 32, n0 = blockIdx.x * 32;
    const int r = threadIdx.x >> 3, c4 = (threadIdx.x & 7) * 4;
    *(float4*)&tl[r][c4] = *(const float4*)(W + (size_t)(k0 + r) * DM + n0 + c4);
    __syncthreads();
    unsigned u0 = (unsigned short)f2bf(tl[c4+0][r]) | ((unsigned)(unsigned short)f2bf(tl[c4+1][r]) << 16);
    unsigned u1 = (unsigned short)f2bf(tl[c4+2][r]) | ((unsigned)(unsigned short)f2bf(tl[c4+3][r]) << 16);
    uint2 pk; pk.x = u0; pk.y = u1;
    *(uint2*)(Wt + (size_t)(n0 + r) * DM + k0 + c4) = pk;
}

// ---------------- bf16 MFMA GEMM: C = A @ Wt^T + bias ----------------
// AF32=1: A is f32 (converted during staging). AF32=0: A bf16.
template<int AF32>
__device__ inline void loadA(const void* Av, size_t elemoff, s16x8& a0, s16x8& a1) {
    if constexpr (AF32) {
        const float* p = (const float*)Av + elemoff;
        f32x4 v0 = *(const f32x4*)p,     v1 = *(const f32x4*)(p + 4);
        f32x4 v2 = *(const f32x4*)(p + 8), v3 = *(const f32x4*)(p + 12);
        a0[0]=f2bf(v0[0]); a0[1]=f2bf(v0[1]); a0[2]=f2bf(v0[2]); a0[3]=f2bf(v0[3]);
        a0[4]=f2bf(v1[0]); a0[5]=f2bf(v1[1]); a0[6]=f2bf(v1[2]); a0[7]=f2bf(v1[3]);
        a1[0]=f2bf(v2[0]); a1[1]=f2bf(v2[1]); a1[2]=f2bf(v2[2]); a1[3]=f2bf(v2[3]);
        a1[4]=f2bf(v3[0]); a1[5]=f2bf(v3[1]); a1[6]=f2bf(v3[2]); a1[7]=f2bf(v3[3]);
    } else {
        const short* p = (const short*)Av + elemoff;
        a0 = *(const s16x8*)p;
        a1 = *(const s16x8*)(p + 8);
    }
}

template<int AF32>
__global__ __launch_bounds__(256) void gemm_bf16(
    const void* __restrict__ Av, const short* __restrict__ Wt,
    const float* __restrict__ bias, const float* __restrict__ resid,
    void* __restrict__ outp, int mode)
{
    const int t  = threadIdx.x;
    const int wv = t >> 6, l = t & 63, lg = l >> 4, li = l & 15;
    const int wr = wv >> 1, wc = wv & 1;
    const int c0 = blockIdx.x * 64, m0 = blockIdx.y * 64;

    __shared__ short Asl[64 * 64];
    __shared__ short Bsl[64 * 64];

    f32x4 acc[2][2] = {};

    const int sr = t >> 2, scol = (t & 3) * 16;
    const int sw = (sr & 7) << 3;

    s16x8 a0, a1;
    loadA<AF32>(Av, (size_t)(m0 + sr) * DM + scol, a0, a1);
    s16x8 b0 = *(const s16x8*)(Wt + (size_t)(c0 + sr) * DM + scol);
    s16x8 b1 = *(const s16x8*)(Wt + (size_t)(c0 + sr) * DM + scol + 8);

    for (int k0 = 0; k0 < DM; k0 += 64) {
        __syncthreads();
        *(s16x8*)&Asl[sr * 64 + (scol ^ sw)]       = a0;
        *(s16x8*)&Asl[sr * 64 + ((scol + 8) ^ sw)] = a1;
        *(s16x8*)&Bsl[sr * 64 + (scol ^ sw)]       = b0;
        *(s16x8*)&Bsl[sr * 64 + ((scol + 8) ^ sw)] = b1;
        __syncthreads();
        if (k0 + 64 < DM) {
            loadA<AF32>(Av, (size_t)(m0 + sr) * DM + k0 + 64 + scol, a0, a1);
            b0 = *(const s16x8*)(Wt + (size_t)(c0 + sr) * DM + k0 + 64 + scol);
            b1 = *(const s16x8*)(Wt + (size_t)(c0 + sr) * DM + k0 + 64 + scol + 8);
        }
        #pragma unroll
        for (int kh = 0; kh < 2; ++kh) {
            s16x8 af[2], bf[2];
            #pragma unroll
            for (int fi = 0; fi < 2; ++fi) {
                const int row = wr * 32 + fi * 16 + li;
                af[fi] = *(const s16x8*)&Asl[row * 64 + ((kh * 32 + lg * 8) ^ ((row & 7) << 3))];
            }
            #pragma unroll
            for (int fj = 0; fj < 2; ++fj) {
                const int row = wc * 32 + fj * 16 + li;
                bf[fj] = *(const s16x8*)&Bsl[row * 64 + ((kh * 32 + lg * 8) ^ ((row & 7) << 3))];
            }
            #pragma unroll
            for (int fi = 0; fi < 2; ++fi)
                #pragma unroll
                for (int fj = 0; fj < 2; ++fj)
                    acc[fi][fj] = __builtin_amdgcn_mfma_f32_16x16x32_bf16(af[fi], bf[fj], acc[fi][fj], 0, 0, 0);
        }
    }

    const int hh = c0 >> 6;
    #pragma unroll
    for (int fi = 0; fi < 2; ++fi) {
        #pragma unroll
        for (int j = 0; j < 4; ++j) {
            const int m = m0 + wr * 32 + fi * 16 + lg * 4 + j;
            const int bb = m >> 10, n = m & (NSEQ - 1);
            #pragma unroll
            for (int fj = 0; fj < 2; ++fj) {
                const int cc = wc * 32 + fj * 16 + li;
                const int c  = c0 + cc;
                float v = acc[fi][fj][j] + bias[c];
                if (mode == 1) {
                    ((short*)outp)[(((size_t)(bb * H_ + hh) * NSEQ) + n) * DKV + cc] = f2bf(v);
                } else if (mode == 2) {
                    ((short*)outp)[(((size_t)(bb * H_ + hh) * DKV) + cc) * NSEQ + n] = f2bf(v);
                } else {
                    float* of = (float*)outp;
                    of[(size_t)m * DM + c] = v + resid[(size_t)m * DM + c];
                }
            }
        }
    }
}

// ---------------- flash attention, split-K, bf16 MFMA ----------------
// USE_WM=1: scores from pre-fused wm (bf16, tiled [bh][ck][q][64]); masked => wm<0.
// USE_WM=0: direct wgt f32 + mask (fallback when ws too small for wm).
template<bool USE_WM>
__global__ __launch_bounds__(256) void attn_split(
    const short* __restrict__ Qb, const short* __restrict__ Kb, const short* __restrict__ Vt,
    const short* __restrict__ wm,
    const void* __restrict__ mask, const float* __restrict__ wgt,
    const int* __restrict__ flagp, short* __restrict__ Opart,
    float* __restrict__ mpart, float* __restrict__ lpart)
{
    const int t  = threadIdx.x;
    const int wv = t >> 6;
    const int l  = t & 63;
    const int lg = l >> 4;
    const int li = l & 15;
    const int qt = blockIdx.x >> 2;
    const int sp = blockIdx.x & (NSPLIT-1);
    const int h  = blockIdx.y, b = blockIdx.z;
    const size_t bh = (size_t)b * H_ + h;
    const int qrow = qt*64 + wv*16 + li;     // softmax-layout row
    const int kbase = sp * KPB;

    __shared__ short Plds[4][16][80];

    const short* Qp = Qb + (bh * NSEQ + qt*64 + wv*16) * DKV;
    const short* Kp = Kb + bh * NSEQ * DKV;
    const short* Vp = Vt + bh * DKV * NSEQ;
    const float* wrow = wgt + (bh * NSEQ + qrow) * NSEQ;
    const size_t moff = (bh * NSEQ + qrow) * NSEQ;
    int mmode = 0;
    if constexpr (!USE_WM) mmode = *flagp;
    const unsigned* Mi = (const unsigned*)mask;
    const unsigned char* Mb = (const unsigned char*)mask;

    s16x8 qa[2];
    qa[0] = *(const s16x8*)(Qp + (size_t)li * DKV + lg*8);
    qa[1] = *(const s16x8*)(Qp + (size_t)li * DKV + 32 + lg*8);

    float m_run = -1e30f, l_run = 0.f;
    f32x4 oacc[4] = {};

    for (int kc = kbase; kc < kbase + KPB; kc += 64) {
        // S^T = K * Q^T : sc[nt][r] = S[q=li][key=kc+nt*16+lg*4+r]
        f32x4 sc[4] = {};
        #pragma unroll
        for (int dc = 0; dc < 2; ++dc)
            #pragma unroll
            for (int nt = 0; nt < 4; ++nt) {
                s16x8 kb = *(const s16x8*)(Kp + (size_t)(kc + nt*16 + li) * DKV + dc*32 + lg*8);
                sc[nt] = __builtin_amdgcn_mfma_f32_16x16x32_bf16(kb, qa[dc], sc[nt], 0, 0, 0);
            }

        // hoist V fragment loads
        s16x8 vf[8];
        #pragma unroll
        for (int kch = 0; kch < 2; ++kch)
            #pragma unroll
            for (int dt = 0; dt < 4; ++dt)
                vf[kch*4+dt] = *(const s16x8*)(Vp + (size_t)(dt*16 + li) * NSEQ + kc + kch*32 + lg*8);

        // scores -> masked/scaled sv (softmax layout)
        float sv[16];
        float cmax = -1e30f;
        if constexpr (USE_WM) {
            const short* wmp = wm + (((size_t)bh * WMCH + (kc >> 6)) * NSEQ + qrow) * 64;
            #pragma unroll
            for (int nt = 0; nt < 4; ++nt) {
                s16x4 wmv = *(const s16x4*)(wmp + nt*16 + lg*4);
                #pragma unroll
                for (int r = 0; r < 4; ++r) {
                    float wf = bf2f(wmv[r]);          // -1 sentinel or 0.125*w
                    float s = sc[nt][r] * wf;
                    s = (wf < 0.f) ? -1e30f : s;
                    sv[nt*4 + r] = s;
                    cmax = fmaxf(cmax, s);
                }
            }
        } else {
            #pragma unroll
            for (int nt = 0; nt < 4; ++nt) {
                const int k4 = kc + nt*16 + lg*4;
                f32x4 w4 = *(const f32x4*)(wrow + k4);
                unsigned mm[4];
                if (mmode) {
                    unsigned u = *(const unsigned*)(Mb + moff + k4);
                    mm[0] = u & 0xffu; mm[1] = (u >> 8) & 0xffu;
                    mm[2] = (u >> 16) & 0xffu; mm[3] = u >> 24;
                } else {
                    u32x4 mi = *(const u32x4*)(Mi + moff + k4);
                    mm[0] = mi[0]; mm[1] = mi[1]; mm[2] = mi[2]; mm[3] = mi[3];
                }
                #pragma unroll
                for (int r = 0; r < 4; ++r) {
                    float s = sc[nt][r] * 0.125f * w4[r];
                    s = mm[r] ? -1e30f : s;
                    sv[nt*4 + r] = s;
                    cmax = fmaxf(cmax, s);
                }
            }
        }
        cmax = fmaxf(cmax, __shfl_xor(cmax, 16));
        cmax = fmaxf(cmax, __shfl_xor(cmax, 32));
        const float mnew = fmaxf(m_run, cmax);
        const float factor = __expf(m_run - mnew);
        m_run = mnew;

        float csum = 0.f;
        #pragma unroll
        for (int nt = 0; nt < 4; ++nt) {
            float p0 = __expf(sv[nt*4+0] - mnew), p1 = __expf(sv[nt*4+1] - mnew);
            float p2 = __expf(sv[nt*4+2] - mnew), p3 = __expf(sv[nt*4+3] - mnew);
            csum += p0 + p1 + p2 + p3;
            unsigned u0 = (unsigned short)f2bf(p0) | ((unsigned)(unsigned short)f2bf(p1) << 16);
            unsigned u1 = (unsigned short)f2bf(p2) | ((unsigned)(unsigned short)f2bf(p3) << 16);
            uint2 pk; pk.x = u0; pk.y = u1;
            *(uint2*)&Plds[wv][li][nt*16 + lg*4] = pk;
        }
        csum += __shfl_xor(csum, 16);
        csum += __shfl_xor(csum, 32);
        l_run = l_run * factor + csum;

        // rescale O in C layout (factor from lane lg*4+r)
        float ffac[4];
        #pragma unroll
        for (int r = 0; r < 4; ++r) ffac[r] = __shfl(factor, lg*4 + r);
        #pragma unroll
        for (int dt = 0; dt < 4; ++dt)
            #pragma unroll
            for (int r = 0; r < 4; ++r)
                oacc[dt][r] *= ffac[r];

        // PV
        #pragma unroll
        for (int kch = 0; kch < 2; ++kch) {
            s16x8 pa = *(const s16x8*)&Plds[wv][li][kch*32 + lg*8];
            #pragma unroll
            for (int dt = 0; dt < 4; ++dt)
                oacc[dt] = __builtin_amdgcn_mfma_f32_16x16x32_bf16(pa, vf[kch*4+dt], oacc[dt], 0, 0, 0);
        }
    }

    // ---- write partials ----
    const size_t SBH = (size_t)B_ * H_ * NSEQ;
    if (lg == 0) {
        mpart[(size_t)sp * SBH + bh * NSEQ + qrow] = m_run;
        lpart[(size_t)sp * SBH + bh * NSEQ + qrow] = l_run;
    }
    #pragma unroll
    for (int dt = 0; dt < 4; ++dt)
        #pragma unroll
        for (int r = 0; r < 4; ++r)
            Opart[((size_t)sp * SBH + bh * NSEQ + qt*64 + wv*16 + lg*4 + r) * DKV + dt*16 + li]
                = f2bf(oacc[dt][r]);
}

// ---------------- split combine ----------------
__global__ __launch_bounds__(256) void attn_combine(
    const short* __restrict__ Opart, const float* __restrict__ mpart,
    const float* __restrict__ lpart, short* __restrict__ Ob)
{
    const size_t SBH = (size_t)B_ * H_ * NSEQ;
    const int R = blockIdx.x * 4 + (threadIdx.x >> 6);
    const int d = threadIdx.x & 63;
    const int bh = R >> 10, n = R & (NSEQ - 1);
    const int b = bh >> 4, h = bh & (H_ - 1);

    float ms[NSPLIT];
    float mstar = -1e30f;
    #pragma unroll
    for (int s = 0; s < NSPLIT; ++s) {
        ms[s] = mpart[(size_t)s * SBH + R];
        mstar = fmaxf(mstar, ms[s]);
    }
    float lstar = 0.f, acc = 0.f;
    #pragma unroll
    for (int s = 0; s < NSPLIT; ++s) {
        float w = __expf(ms[s] - mstar);
        lstar += w * lpart[(size_t)s * SBH + R];
        acc   += w * bf2f(Opart[((size_t)s * SBH + R) * DKV + d]);
    }
    Ob[((size_t)b * NSEQ + n) * DM + h * DKV + d] = f2bf(acc / lstar);
}

// ---------------- residual + LayerNorm ----------------
__global__ __launch_bounds__(256) void ln_kernel(
    const float* __restrict__ Y, const float* __restrict__ gamma,
    const float* __restrict__ beta, float* __restrict__ out)
{
    const int row = blockIdx.x;
    const int t = threadIdx.x;
    const float* y = Y + (size_t)row * DM;
    float4 x = *(const float4*)(y + t*4);
    __shared__ float red[4];
    float s = x.x + x.y + x.z + x.w;
    #pragma unroll
    for (int off = 32; off > 0; off >>= 1) s += __shfl_xor(s, off);
    if ((t & 63) == 0) red[t >> 6] = s;
    __syncthreads();
    float mean = (red[0]+red[1]+red[2]+red[3]) * (1.0f/DM);
    float d0 = x.x-mean, d1 = x.y-mean, d2 = x.z-mean, d3 = x.w-mean;
    float sq = d0*d0 + d1*d1 + d2*d2 + d3*d3;
    __syncthreads();
    #pragma unroll
    for (int off = 32; off > 0; off >>= 1) sq += __shfl_xor(sq, off);
    if ((t & 63) == 0) red[t >> 6] = sq;
    __syncthreads();
    float var = (red[0]+red[1]+red[2]+red[3]) * (1.0f/DM);
    float rstd = rsqrtf(var + LNEPS);
    int c = t * 4;
    float4 g  = *(const float4*)(gamma + c);
    float4 bb = *(const float4*)(beta + c);
    float4 o;
    o.x = d0*rstd*g.x + bb.x;
    o.y = d1*rstd*g.y + bb.y;
    o.z = d2*rstd*g.z + bb.z;
    o.w = d3*rstd*g.w + bb.w;
    *(float4*)(out + (size_t)row*DM + c) = o;
}

extern "C" void kernel_launch(void* const* d_in, const int* in_sizes, int n_in,
                              void* d_out, int out_size, void* d_ws, size_t ws_size,
                              hipStream_t stream)
{
    const float* queries = (const float*)d_in[0];
    const float* keys    = (const float*)d_in[1];
    const float* values  = (const float*)d_in[2];
    const void*  mask    = d_in[3];
    const float* wgt     = (const float*)d_in[4];
    const float* Wq = (const float*)d_in[5];  const float* bq = (const float*)d_in[6];
    const float* Wk = (const float*)d_in[7];  const float* bk = (const float*)d_in[8];
    const float* Wv = (const float*)d_in[9];  const float* bv = (const float*)d_in[10];
    const float* Wo = (const float*)d_in[11]; const float* bo = (const float*)d_in[12];
    const float* gamma = (const float*)d_in[13]; const float* beta = (const float*)d_in[14];
    float* out = (float*)d_out;

    const size_t SZ  = (size_t)B_ * NSEQ * DM;     // 2M elements
    const size_t WSZ = (size_t)DM * DM;            // 1M elements
    const size_t SBH = (size_t)B_ * H_ * NSEQ;     // 32K rows
    const size_t WMSZ = (size_t)B_ * H_ * WMCH * NSEQ * 64;   // 32M elements

    char* ws = (char*)d_ws;
    int*   flag = (int*)ws;
    short* Wtq = (short*)(ws + 256);
    short* Wtk = Wtq + WSZ;
    short* Wtv = Wtk + WSZ;
    short* Wto = Wtv + WSZ;
    short* Qh  = Wto + WSZ;
    short* Kh  = Qh + SZ;
    short* Vth = Kh + SZ;
    short* Opart = Vth + SZ;
    float* mpart = (float*)(Opart + (size_t)NSPLIT * SBH * DKV);
    float* lpart = mpart + NSPLIT * SBH;
    short* Ob  = (short*)(lpart + NSPLIT * SBH);
    float* Yb  = (float*)(Ob + SZ);
    short* wm  = (short*)(Yb + SZ);
    const size_t req = (size_t)((char*)(wm + WMSZ) - ws);
    const bool use_wm = ws_size >= req;

    detect_mask<<<1, 1, 0, stream>>>((const unsigned*)mask, flag);
    castT4_bf16<<<dim3(32, 32, 4), 256, 0, stream>>>(Wq, Wk, Wv, Wo, Wtq, Wtk, Wtv, Wto);

    gemm_bf16<1><<<dim3(16, 32), 256, 0, stream>>>(queries, Wtq, bq, nullptr, Qh, 1);
    gemm_bf16<1><<<dim3(16, 32), 256, 0, stream>>>(keys,    Wtk, bk, nullptr, Kh, 1);
    gemm_bf16<1><<<dim3(16, 32), 256, 0, stream>>>(values,  Wtv, bv, nullptr, Vth, 2);

    if (use_wm) {
        wm_stream<<<dim3(16, H_, B_), 256, 0, stream>>>(mask, wgt, flag, wm);
        attn_split<true><<<dim3(16 * NSPLIT, H_, B_), 256, 0, stream>>>(
            Qh, Kh, Vth, wm, mask, wgt, flag, Opart, mpart, lpart);
    } else {
        attn_split<false><<<dim3(16 * NSPLIT, H_, B_), 256, 0, stream>>>(
            Qh, Kh, Vth, nullptr, mask, wgt, flag, Opart, mpart, lpart);
    }
    attn_combine<<<dim3((int)(SBH / 4)), 256, 0, stream>>>(Opart, mpart, lpart, Ob);

    gemm_bf16<0><<<dim3(16, 32), 256, 0, stream>>>(Ob, Wto, bo, queries, Yb, 0);
    ln_kernel<<<dim3(B_*NSEQ), 256, 0, stream>>>(Yb, gamma, beta, out);
}

// Round 7
// 179.130 us; speedup vs baseline: 1.4614x; 1.4614x over previous
//
#include <hip/hip_runtime.h>
#include <hip/hip_bf16.h>
#include <math.h>

#define B_   2
#define H_   16
#define NSEQ 1024
#define DM   1024
#define DKV  64
#define NSPLIT 4
#define KPB  (NSEQ / NSPLIT)   // 256 keys per block
#define LNEPS 1e-5f

typedef __attribute__((ext_vector_type(8))) short s16x8;
typedef __attribute__((ext_vector_type(4))) float f32x4;
typedef __attribute__((ext_vector_type(4))) unsigned u32x4;

__device__ inline short f2bf(float f) {
    __hip_bfloat16 h = __float2bfloat16(f);
    return *reinterpret_cast<short*>(&h);
}
__device__ inline float bf2f(short s) {
    unsigned u = ((unsigned)(unsigned short)s) << 16;
    return __uint_as_float(u);
}

// async global->LDS, 16B per lane; LDS dest = wave-uniform base + lane*16
__device__ __forceinline__ void gll16(const short* g, short* l) {
    __builtin_amdgcn_global_load_lds(
        (const __attribute__((address_space(1))) unsigned int*)g,
        (__attribute__((address_space(3))) unsigned int*)l, 16, 0, 0);
}

// ---------------- mask dtype detection ----------------
__global__ void detect_mask(const unsigned* __restrict__ mask_words, int* __restrict__ flag) {
    unsigned f = 0;
    for (int i = 0; i < 256; ++i) f |= (mask_words[i] > 1u) ? 1u : 0u;
    *flag = (int)f;   // 1 => packed uint8 bools, 0 => int32 0/1
}

// ---------------- W[K][N] f32 -> Wt[N][K] bf16 (4 weights in one launch) ----------------
__global__ __launch_bounds__(256) void castT4_bf16(
    const float* __restrict__ w0, const float* __restrict__ w1,
    const float* __restrict__ w2, const float* __restrict__ w3,
    short* __restrict__ t0, short* __restrict__ t1,
    short* __restrict__ t2, short* __restrict__ t3) {
    const float* W = blockIdx.z == 0 ? w0 : (blockIdx.z == 1 ? w1 : (blockIdx.z == 2 ? w2 : w3));
    short* Wt      = blockIdx.z == 0 ? t0 : (blockIdx.z == 1 ? t1 : (blockIdx.z == 2 ? t2 : t3));
    __shared__ float tl[32][33];
    const int k0 = blockIdx.y * 32, n0 = blockIdx.x * 32;
    const int r = threadIdx.x >> 3, c4 = (threadIdx.x & 7) * 4;
    *(float4*)&tl[r][c4] = *(const float4*)(W + (size_t)(k0 + r) * DM + n0 + c4);
    __syncthreads();
    unsigned u0 = (unsigned short)f2bf(tl[c4+0][r]) | ((unsigned)(unsigned short)f2bf(tl[c4+1][r]) << 16);
    unsigned u1 = (unsigned short)f2bf(tl[c4+2][r]) | ((unsigned)(unsigned short)f2bf(tl[c4+3][r]) << 16);
    uint2 pk; pk.x = u0; pk.y = u1;
    *(uint2*)(Wt + (size_t)(n0 + r) * DM + k0 + c4) = pk;
}

// ---------------- bf16 MFMA GEMM: C = A @ Wt^T + bias ----------------
template<int AF32>
__device__ inline void loadA(const void* Av, size_t elemoff, s16x8& a0, s16x8& a1) {
    if constexpr (AF32) {
        const float* p = (const float*)Av + elemoff;
        f32x4 v0 = *(const f32x4*)p,     v1 = *(const f32x4*)(p + 4);
        f32x4 v2 = *(const f32x4*)(p + 8), v3 = *(const f32x4*)(p + 12);
        a0[0]=f2bf(v0[0]); a0[1]=f2bf(v0[1]); a0[2]=f2bf(v0[2]); a0[3]=f2bf(v0[3]);
        a0[4]=f2bf(v1[0]); a0[5]=f2bf(v1[1]); a0[6]=f2bf(v1[2]); a0[7]=f2bf(v1[3]);
        a1[0]=f2bf(v2[0]); a1[1]=f2bf(v2[1]); a1[2]=f2bf(v2[2]); a1[3]=f2bf(v2[3]);
        a1[4]=f2bf(v3[0]); a1[5]=f2bf(v3[1]); a1[6]=f2bf(v3[2]); a1[7]=f2bf(v3[3]);
    } else {
        const short* p = (const short*)Av + elemoff;
        a0 = *(const s16x8*)p;
        a1 = *(const s16x8*)(p + 8);
    }
}

template<int AF32>
__global__ __launch_bounds__(256) void gemm_bf16(
    const void* __restrict__ Av, const short* __restrict__ Wt,
    const float* __restrict__ bias, const float* __restrict__ resid,
    void* __restrict__ outp, int mode)
{
    const int t  = threadIdx.x;
    const int wv = t >> 6, l = t & 63, lg = l >> 4, li = l & 15;
    const int wr = wv >> 1, wc = wv & 1;
    const int c0 = blockIdx.x * 64, m0 = blockIdx.y * 64;

    __shared__ short Asl[64 * 64];
    __shared__ short Bsl[64 * 64];

    f32x4 acc[2][2] = {};

    const int sr = t >> 2, scol = (t & 3) * 16;
    const int sw = (sr & 7) << 3;

    s16x8 a0, a1;
    loadA<AF32>(Av, (size_t)(m0 + sr) * DM + scol, a0, a1);
    s16x8 b0 = *(const s16x8*)(Wt + (size_t)(c0 + sr) * DM + scol);
    s16x8 b1 = *(const s16x8*)(Wt + (size_t)(c0 + sr) * DM + scol + 8);

    for (int k0 = 0; k0 < DM; k0 += 64) {
        __syncthreads();
        *(s16x8*)&Asl[sr * 64 + (scol ^ sw)]       = a0;
        *(s16x8*)&Asl[sr * 64 + ((scol + 8) ^ sw)] = a1;
        *(s16x8*)&Bsl[sr * 64 + (scol ^ sw)]       = b0;
        *(s16x8*)&Bsl[sr * 64 + ((scol + 8) ^ sw)] = b1;
        __syncthreads();
        if (k0 + 64 < DM) {
            loadA<AF32>(Av, (size_t)(m0 + sr) * DM + k0 + 64 + scol, a0, a1);
            b0 = *(const s16x8*)(Wt + (size_t)(c0 + sr) * DM + k0 + 64 + scol);
            b1 = *(const s16x8*)(Wt + (size_t)(c0 + sr) * DM + k0 + 64 + scol + 8);
        }
        #pragma unroll
        for (int kh = 0; kh < 2; ++kh) {
            s16x8 af[2], bf[2];
            #pragma unroll
            for (int fi = 0; fi < 2; ++fi) {
                const int row = wr * 32 + fi * 16 + li;
                af[fi] = *(const s16x8*)&Asl[row * 64 + ((kh * 32 + lg * 8) ^ ((row & 7) << 3))];
            }
            #pragma unroll
            for (int fj = 0; fj < 2; ++fj) {
                const int row = wc * 32 + fj * 16 + li;
                bf[fj] = *(const s16x8*)&Bsl[row * 64 + ((kh * 32 + lg * 8) ^ ((row & 7) << 3))];
            }
            #pragma unroll
            for (int fi = 0; fi < 2; ++fi)
                #pragma unroll
                for (int fj = 0; fj < 2; ++fj)
                    acc[fi][fj] = __builtin_amdgcn_mfma_f32_16x16x32_bf16(af[fi], bf[fj], acc[fi][fj], 0, 0, 0);
        }
    }

    const int hh = c0 >> 6;
    #pragma unroll
    for (int fi = 0; fi < 2; ++fi) {
        #pragma unroll
        for (int j = 0; j < 4; ++j) {
            const int m = m0 + wr * 32 + fi * 16 + lg * 4 + j;
            const int bb = m >> 10, n = m & (NSEQ - 1);
            #pragma unroll
            for (int fj = 0; fj < 2; ++fj) {
                const int cc = wc * 32 + fj * 16 + li;
                const int c  = c0 + cc;
                float v = acc[fi][fj][j] + bias[c];
                if (mode == 1) {
                    ((short*)outp)[(((size_t)(bb * H_ + hh) * NSEQ) + n) * DKV + cc] = f2bf(v);
                } else if (mode == 2) {
                    ((short*)outp)[(((size_t)(bb * H_ + hh) * DKV) + cc) * NSEQ + n] = f2bf(v);
                } else {
                    float* of = (float*)outp;
                    of[(size_t)m * DM + c] = v + resid[(size_t)m * DM + c];
                }
            }
        }
    }
}

// ---------------- flash attention split-K, LDS-staged K/V, prefetched wgt/mask ----------------
// Per chunk (64 keys): stage next chunk's K/V via async global_load_lds (linear LDS dest,
// inverse-XOR-swizzled global source; ds_read applies same XOR -> conflict-free, rule-21).
// wgt/mask for next chunk prefetched into regs pre-fused: wq = masked ? -1 : 0.125*w.
// One vmcnt(0)+barrier per chunk; staged loads overlap the whole compute phase.

// prefetch wgt+mask for one 64-key chunk (16 values per lane, softmax layout)
__device__ __forceinline__ void wload(
    const float* __restrict__ wrow, const unsigned char* __restrict__ Mb,
    const unsigned* __restrict__ Mi, size_t moff, int mmode, int kc, int lg, f32x4* wq)
{
    #pragma unroll
    for (int nt = 0; nt < 4; ++nt) {
        const int k4 = kc + nt*16 + lg*4;
        f32x4 w4 = *(const f32x4*)(wrow + k4);
        unsigned mm[4];
        if (mmode) {
            unsigned u = *(const unsigned*)(Mb + moff + k4);
            mm[0]=u&0xffu; mm[1]=(u>>8)&0xffu; mm[2]=(u>>16)&0xffu; mm[3]=u>>24;
        } else {
            u32x4 mi = *(const u32x4*)(Mi + moff + k4);
            mm[0]=mi[0]; mm[1]=mi[1]; mm[2]=mi[2]; mm[3]=mi[3];
        }
        f32x4 o;
        #pragma unroll
        for (int r = 0; r < 4; ++r) o[r] = mm[r] ? -1.0f : 0.125f * w4[r];
        wq[nt] = o;
    }
}

// async-stage 64x64 K chunk + 64x64 V chunk into LDS (source pre-swizzled)
__device__ __forceinline__ void stage_kv(
    const short* __restrict__ Kp, const short* __restrict__ Vp, int kc,
    short* Kl, short* Vl, int wv, int l)
{
    const int g = (l & 7) ^ ((l >> 3) & 7);   // inverse swizzle (involution)
    #pragma unroll
    for (int j = 0; j < 2; ++j) {
        const int r = wv*16 + j*8 + (l >> 3);
        gll16(Kp + (size_t)(kc + r) * DKV + g*8, Kl + (wv*16 + j*8) * 64);
        gll16(Vp + (size_t)r * NSEQ + kc + g*8,  Vl + (wv*16 + j*8) * 64);
    }
}

// process one 64-key chunk from LDS
__device__ __forceinline__ void attn_chunk(
    const short* __restrict__ Kc, const short* __restrict__ Vc,
    const f32x4* wq, const s16x8* qa, short* Pb,
    const int lg, const int li,
    float& m_run, float& l_run, f32x4* oacc)
{
    // S^T = K * Q^T : sc[nt][r] = S[q=li][key = nt*16 + lg*4 + r]
    f32x4 sc[4] = {};
    #pragma unroll
    for (int dc = 0; dc < 2; ++dc)
        #pragma unroll
        for (int nt = 0; nt < 4; ++nt) {
            const int row = nt*16 + li;
            s16x8 kb = *(const s16x8*)&Kc[row*64 + (((dc*4 + lg) ^ (row & 7)) << 3)];
            sc[nt] = __builtin_amdgcn_mfma_f32_16x16x32_bf16(kb, qa[dc], sc[nt], 0, 0, 0);
        }

    float sv[16];
    float cmax = -1e30f;
    #pragma unroll
    for (int nt = 0; nt < 4; ++nt)
        #pragma unroll
        for (int r = 0; r < 4; ++r) {
            float wf = wq[nt][r];                 // -1 sentinel or 0.125*w
            float s = sc[nt][r] * wf;
            s = (wf < 0.f) ? -1e30f : s;
            sv[nt*4 + r] = s;
            cmax = fmaxf(cmax, s);
        }
    cmax = fmaxf(cmax, __shfl_xor(cmax, 16));
    cmax = fmaxf(cmax, __shfl_xor(cmax, 32));
    const float mnew = fmaxf(m_run, cmax);
    const float factor = __expf(m_run - mnew);
    m_run = mnew;

    float csum = 0.f;
    #pragma unroll
    for (int nt = 0; nt < 4; ++nt) {
        float p0 = __expf(sv[nt*4+0] - mnew), p1 = __expf(sv[nt*4+1] - mnew);
        float p2 = __expf(sv[nt*4+2] - mnew), p3 = __expf(sv[nt*4+3] - mnew);
        csum += p0 + p1 + p2 + p3;
        unsigned u0 = (unsigned short)f2bf(p0) | ((unsigned)(unsigned short)f2bf(p1) << 16);
        unsigned u1 = (unsigned short)f2bf(p2) | ((unsigned)(unsigned short)f2bf(p3) << 16);
        uint2 pk; pk.x = u0; pk.y = u1;
        *(uint2*)&Pb[li*80 + nt*16 + lg*4] = pk;
    }
    csum += __shfl_xor(csum, 16);
    csum += __shfl_xor(csum, 32);
    l_run = l_run * factor + csum;

    // rescale O in C layout (factor from lane lg*4+r)
    float ffac[4];
    #pragma unroll
    for (int r = 0; r < 4; ++r) ffac[r] = __shfl(factor, lg*4 + r);
    #pragma unroll
    for (int dt = 0; dt < 4; ++dt)
        #pragma unroll
        for (int r = 0; r < 4; ++r)
            oacc[dt][r] *= ffac[r];

    // PV from LDS V
    #pragma unroll
    for (int kch = 0; kch < 2; ++kch) {
        s16x8 pa = *(const s16x8*)&Pb[li*80 + kch*32 + lg*8];
        #pragma unroll
        for (int dt = 0; dt < 4; ++dt) {
            const int row = dt*16 + li;
            s16x8 vb = *(const s16x8*)&Vc[row*64 + (((kch*4 + lg) ^ (row & 7)) << 3)];
            oacc[dt] = __builtin_amdgcn_mfma_f32_16x16x32_bf16(pa, vb, oacc[dt], 0, 0, 0);
        }
    }
}

#define SYNC_CHUNK do { asm volatile("s_waitcnt vmcnt(0)" ::: "memory"); __syncthreads(); } while (0)

__global__ __launch_bounds__(256) void attn_split(
    const short* __restrict__ Qb, const short* __restrict__ Kb, const short* __restrict__ Vt,
    const void* __restrict__ mask, const float* __restrict__ wgt,
    const int* __restrict__ flagp, short* __restrict__ Opart,
    float* __restrict__ mpart, float* __restrict__ lpart)
{
    const int t  = threadIdx.x;
    const int wv = t >> 6;
    const int l  = t & 63;
    const int lg = l >> 4;
    const int li = l & 15;
    const int qt = blockIdx.x >> 2;
    const int sp = blockIdx.x & (NSPLIT-1);
    const int h  = blockIdx.y, b = blockIdx.z;
    const size_t bh = (size_t)b * H_ + h;
    const int qrow = qt*64 + wv*16 + li;     // softmax-layout row
    const int kbase = sp * KPB;

    __shared__ short Kl[2][4096];
    __shared__ short Vl[2][4096];
    __shared__ short Plds[4][16][80];

    const short* Qp = Qb + (bh * NSEQ + qt*64 + wv*16) * DKV;
    const short* Kp = Kb + bh * NSEQ * DKV;
    const short* Vp = Vt + bh * DKV * NSEQ;
    const float* wrow = wgt + (bh * NSEQ + qrow) * NSEQ;
    const size_t moff = (bh * NSEQ + qrow) * NSEQ;
    const int mmode = *flagp;
    const unsigned* Mi = (const unsigned*)mask;
    const unsigned char* Mb = (const unsigned char*)mask;

    s16x8 qa[2];
    qa[0] = *(const s16x8*)(Qp + (size_t)li * DKV + lg*8);
    qa[1] = *(const s16x8*)(Qp + (size_t)li * DKV + 32 + lg*8);

    float m_run = -1e30f, l_run = 0.f;
    f32x4 oacc[4] = {};
    f32x4 wA[4], wB[4];
    short* Pb = &Plds[wv][0][0];

    // prologue: chunk0 staged + its wgt/mask prefetched
    stage_kv(Kp, Vp, kbase,       Kl[0], Vl[0], wv, l);
    wload(wrow, Mb, Mi, moff, mmode, kbase, lg, wA);
    SYNC_CHUNK;

    stage_kv(Kp, Vp, kbase + 64,  Kl[1], Vl[1], wv, l);
    wload(wrow, Mb, Mi, moff, mmode, kbase + 64, lg, wB);
    attn_chunk(Kl[0], Vl[0], wA, qa, Pb, lg, li, m_run, l_run, oacc);   // chunk 0
    SYNC_CHUNK;

    stage_kv(Kp, Vp, kbase + 128, Kl[0], Vl[0], wv, l);
    wload(wrow, Mb, Mi, moff, mmode, kbase + 128, lg, wA);
    attn_chunk(Kl[1], Vl[1], wB, qa, Pb, lg, li, m_run, l_run, oacc);   // chunk 1
    SYNC_CHUNK;

    stage_kv(Kp, Vp, kbase + 192, Kl[1], Vl[1], wv, l);
    wload(wrow, Mb, Mi, moff, mmode, kbase + 192, lg, wB);
    attn_chunk(Kl[0], Vl[0], wA, qa, Pb, lg, li, m_run, l_run, oacc);   // chunk 2
    SYNC_CHUNK;

    attn_chunk(Kl[1], Vl[1], wB, qa, Pb, lg, li, m_run, l_run, oacc);   // chunk 3

    // ---- write partials ----
    const size_t SBH = (size_t)B_ * H_ * NSEQ;
    if (lg == 0) {
        mpart[(size_t)sp * SBH + bh * NSEQ + qrow] = m_run;
        lpart[(size_t)sp * SBH + bh * NSEQ + qrow] = l_run;
    }
    #pragma unroll
    for (int dt = 0; dt < 4; ++dt)
        #pragma unroll
        for (int r = 0; r < 4; ++r)
            Opart[((size_t)sp * SBH + bh * NSEQ + qt*64 + wv*16 + lg*4 + r) * DKV + dt*16 + li]
                = f2bf(oacc[dt][r]);
}

// ---------------- split combine ----------------
__global__ __launch_bounds__(256) void attn_combine(
    const short* __restrict__ Opart, const float* __restrict__ mpart,
    const float* __restrict__ lpart, short* __restrict__ Ob)
{
    const size_t SBH = (size_t)B_ * H_ * NSEQ;
    const int R = blockIdx.x * 4 + (threadIdx.x >> 6);
    const int d = threadIdx.x & 63;
    const int bh = R >> 10, n = R & (NSEQ - 1);
    const int b = bh >> 4, h = bh & (H_ - 1);

    float ms[NSPLIT];
    float mstar = -1e30f;
    #pragma unroll
    for (int s = 0; s < NSPLIT; ++s) {
        ms[s] = mpart[(size_t)s * SBH + R];
        mstar = fmaxf(mstar, ms[s]);
    }
    float lstar = 0.f, acc = 0.f;
    #pragma unroll
    for (int s = 0; s < NSPLIT; ++s) {
        float w = __expf(ms[s] - mstar);
        lstar += w * lpart[(size_t)s * SBH + R];
        acc   += w * bf2f(Opart[((size_t)s * SBH + R) * DKV + d]);
    }
    Ob[((size_t)b * NSEQ + n) * DM + h * DKV + d] = f2bf(acc / lstar);
}

// ---------------- residual + LayerNorm ----------------
__global__ __launch_bounds__(256) void ln_kernel(
    const float* __restrict__ Y, const float* __restrict__ gamma,
    const float* __restrict__ beta, float* __restrict__ out)
{
    const int row = blockIdx.x;
    const int t = threadIdx.x;
    const float* y = Y + (size_t)row * DM;
    float4 x = *(const float4*)(y + t*4);
    __shared__ float red[4];
    float s = x.x + x.y + x.z + x.w;
    #pragma unroll
    for (int off = 32; off > 0; off >>= 1) s += __shfl_xor(s, off);
    if ((t & 63) == 0) red[t >> 6] = s;
    __syncthreads();
    float mean = (red[0]+red[1]+red[2]+red[3]) * (1.0f/DM);
    float d0 = x.x-mean, d1 = x.y-mean, d2 = x.z-mean, d3 = x.w-mean;
    float sq = d0*d0 + d1*d1 + d2*d2 + d3*d3;
    __syncthreads();
    #pragma unroll
    for (int off = 32; off > 0; off >>= 1) sq += __shfl_xor(sq, off);
    if ((t & 63) == 0) red[t >> 6] = sq;
    __syncthreads();
    float var = (red[0]+red[1]+red[2]+red[3]) * (1.0f/DM);
    float rstd = rsqrtf(var + LNEPS);
    int c = t * 4;
    float4 g  = *(const float4*)(gamma + c);
    float4 bb = *(const float4*)(beta + c);
    float4 o;
    o.x = d0*rstd*g.x + bb.x;
    o.y = d1*rstd*g.y + bb.y;
    o.z = d2*rstd*g.z + bb.z;
    o.w = d3*rstd*g.w + bb.w;
    *(float4*)(out + (size_t)row*DM + c) = o;
}

extern "C" void kernel_launch(void* const* d_in, const int* in_sizes, int n_in,
                              void* d_out, int out_size, void* d_ws, size_t ws_size,
                              hipStream_t stream)
{
    const float* queries = (const float*)d_in[0];
    const float* keys    = (const float*)d_in[1];
    const float* values  = (const float*)d_in[2];
    const void*  mask    = d_in[3];
    const float* wgt     = (const float*)d_in[4];
    const float* Wq = (const float*)d_in[5];  const float* bq = (const float*)d_in[6];
    const float* Wk = (const float*)d_in[7];  const float* bk = (const float*)d_in[8];
    const float* Wv = (const float*)d_in[9];  const float* bv = (const float*)d_in[10];
    const float* Wo = (const float*)d_in[11]; const float* bo = (const float*)d_in[12];
    const float* gamma = (const float*)d_in[13]; const float* beta = (const float*)d_in[14];
    float* out = (float*)d_out;

    const size_t SZ  = (size_t)B_ * NSEQ * DM;     // 2M elements
    const size_t WSZ = (size_t)DM * DM;            // 1M elements
    const size_t SBH = (size_t)B_ * H_ * NSEQ;     // 32K rows

    char* ws = (char*)d_ws;
    int*   flag = (int*)ws;
    short* Wtq = (short*)(ws + 256);
    short* Wtk = Wtq + WSZ;
    short* Wtv = Wtk + WSZ;
    short* Wto = Wtv + WSZ;
    short* Qh  = Wto + WSZ;
    short* Kh  = Qh + SZ;
    short* Vth = Kh + SZ;
    short* Opart = Vth + SZ;
    float* mpart = (float*)(Opart + (size_t)NSPLIT * SBH * DKV);
    float* lpart = mpart + NSPLIT * SBH;
    short* Ob  = (short*)(lpart + NSPLIT * SBH);
    float* Yb  = (float*)(Ob + SZ);

    detect_mask<<<1, 1, 0, stream>>>((const unsigned*)mask, flag);
    castT4_bf16<<<dim3(32, 32, 4), 256, 0, stream>>>(Wq, Wk, Wv, Wo, Wtq, Wtk, Wtv, Wto);

    gemm_bf16<1><<<dim3(16, 32), 256, 0, stream>>>(queries, Wtq, bq, nullptr, Qh, 1);
    gemm_bf16<1><<<dim3(16, 32), 256, 0, stream>>>(keys,    Wtk, bk, nullptr, Kh, 1);
    gemm_bf16<1><<<dim3(16, 32), 256, 0, stream>>>(values,  Wtv, bv, nullptr, Vth, 2);

    attn_split<<<dim3(16 * NSPLIT, H_, B_), 256, 0, stream>>>(
        Qh, Kh, Vth, mask, wgt, flag, Opart, mpart, lpart);
    attn_combine<<<dim3((int)(SBH / 4)), 256, 0, stream>>>(Opart, mpart, lpart, Ob);

    gemm_bf16<0><<<dim3(16, 32), 256, 0, stream>>>(Ob, Wto, bo, queries, Yb, 0);
    ln_kernel<<<dim3(B_*NSEQ), 256, 0, stream>>>(Yb, gamma, beta, out);
}